// Round 5
// baseline (409.684 us; speedup 1.0000x reference)
//
#include <hip/hip_runtime.h>

// SSIM, 64 slices of 512x512, 11x11 uniform window (separable box), zero pad.
// R5: wave-autonomous, BAND=4 for 2x waves (8192 waves, 8 blocks/CU, 32
// waves/CU). Latency-bound per R4 counters (VALU 26%, HBM 30%, occ 38%) --
// parallelism is the binding constraint, so trade work-efficiency for TLP.
// VGPR must stay <= 64 (8 waves/SIMD cliff) -- no register prefetch.
//  - each wave owns a 4-output-row band x full 512 cols (8 cols/lane).
//  - vertical running box sums in registers; "subtract row r-11" re-loaded
//    from global (L2/L3-hot).
//  - horizontal 11-box via 10 lane shuffles per quantity (conflict-free).

constexpr int IMG    = 512;
constexpr int BAND   = 4;                       // output rows per wave
constexpr int BANDS  = IMG / BAND;              // 128
constexpr int WPB    = 4;                       // waves per block
constexpr int BX     = BANDS / WPB;             // 32 blocks in x
constexpr float WSCALE = 1.0f / 121.0f;
constexpr float C1F = 1e-4f;                    // 0.01^2
constexpr float C2F = 9e-4f;                    // 0.03^2

__device__ __forceinline__ float shl1(float v, int lane) {  // lane g-1's v, 0 at g==0
  const float t = __shfl_up(v, 1, 64);
  return lane == 0 ? 0.f : t;
}
__device__ __forceinline__ float shr1(float v, int lane) {  // lane g+1's v, 0 at g==63
  const float t = __shfl_down(v, 1, 64);
  return lane == 63 ? 0.f : t;
}

// horizontal 11-wide box sum of per-column sums c[0..7] (cols 8g..8g+7),
// zero padding outside [0,512). h[j] = sum cols (8g+j-5 .. 8g+j+5).
__device__ __forceinline__ void hbox11(const float c[8], int lane, float h[8]) {
  float w[18];
  w[0] = shl1(c[3], lane);
  w[1] = shl1(c[4], lane);
  w[2] = shl1(c[5], lane);
  w[3] = shl1(c[6], lane);
  w[4] = shl1(c[7], lane);
#pragma unroll
  for (int k = 0; k < 8; ++k) w[5 + k] = c[k];
  w[13] = shr1(c[0], lane);
  w[14] = shr1(c[1], lane);
  w[15] = shr1(c[2], lane);
  w[16] = shr1(c[3], lane);
  w[17] = shr1(c[4], lane);
  float s = w[0];
#pragma unroll
  for (int k = 1; k <= 10; ++k) s += w[k];
  h[0] = s;
#pragma unroll
  for (int j = 1; j < 8; ++j) { s += w[j + 10] - w[j - 1]; h[j] = s; }
}

template <bool ATOMIC>
__global__ __launch_bounds__(256, 8) void ssim_main(const float* __restrict__ x,
                                                    const float* __restrict__ y,
                                                    float* __restrict__ out_ws) {
  const int tid  = threadIdx.x;
  const int lane = tid & 63;
  const int wv   = tid >> 6;
  const int band = blockIdx.x * WPB + wv;   // 0..127
  const int z    = blockIdx.y;              // 0..63
  const int O0   = band * BAND;             // first output row
  const int r0   = O0 - 5;                  // first streamed input row
  const float* xs = x + (size_t)z * IMG * IMG;
  const float* ys = y + (size_t)z * IMG * IMG;
  const int c0   = lane * 8;

  float cX[8]  = {0.f,0.f,0.f,0.f,0.f,0.f,0.f,0.f};
  float cY[8]  = {0.f,0.f,0.f,0.f,0.f,0.f,0.f,0.f};
  float cXX[8] = {0.f,0.f,0.f,0.f,0.f,0.f,0.f,0.f};
  float cYY[8] = {0.f,0.f,0.f,0.f,0.f,0.f,0.f,0.f};
  float cXY[8] = {0.f,0.f,0.f,0.f,0.f,0.f,0.f,0.f};
  float acc = 0.f;

  auto add_row = [&](int gr) {
    if ((unsigned)gr < (unsigned)IMG) {       // wave-uniform branch
      const float4 a0 = *(const float4*)(xs + (size_t)gr * IMG + c0);
      const float4 a1 = *(const float4*)(xs + (size_t)gr * IMG + c0 + 4);
      const float4 b0 = *(const float4*)(ys + (size_t)gr * IMG + c0);
      const float4 b1 = *(const float4*)(ys + (size_t)gr * IMG + c0 + 4);
      float vx[8] = {a0.x, a0.y, a0.z, a0.w, a1.x, a1.y, a1.z, a1.w};
      float vy[8] = {b0.x, b0.y, b0.z, b0.w, b1.x, b1.y, b1.z, b1.w};
#pragma unroll
      for (int k = 0; k < 8; ++k) {
        cX[k] += vx[k];
        cY[k] += vy[k];
        cXX[k] = fmaf(vx[k], vx[k], cXX[k]);
        cYY[k] = fmaf(vy[k], vy[k], cYY[k]);
        cXY[k] = fmaf(vx[k], vy[k], cXY[k]);
      }
    }
  };
  auto sub_row = [&](int gr) {
    if (gr >= r0 && (unsigned)gr < (unsigned)IMG) {   // never-added rows skipped
      const float4 a0 = *(const float4*)(xs + (size_t)gr * IMG + c0);
      const float4 a1 = *(const float4*)(xs + (size_t)gr * IMG + c0 + 4);
      const float4 b0 = *(const float4*)(ys + (size_t)gr * IMG + c0);
      const float4 b1 = *(const float4*)(ys + (size_t)gr * IMG + c0 + 4);
      float vx[8] = {a0.x, a0.y, a0.z, a0.w, a1.x, a1.y, a1.z, a1.w};
      float vy[8] = {b0.x, b0.y, b0.z, b0.w, b1.x, b1.y, b1.z, b1.w};
#pragma unroll
      for (int k = 0; k < 8; ++k) {
        cX[k] -= vx[k];
        cY[k] -= vy[k];
        cXX[k] = fmaf(-vx[k], vx[k], cXX[k]);
        cYY[k] = fmaf(-vy[k], vy[k], cYY[k]);
        cXY[k] = fmaf(-vx[k], vy[k], cXY[k]);
      }
    }
  };
  auto emit_row = [&]() {
    float hX[8], hY[8], hXX[8], hYY[8], hXY[8];
    hbox11(cX,  lane, hX);
    hbox11(cY,  lane, hY);
    hbox11(cXX, lane, hXX);
    hbox11(cYY, lane, hYY);
    hbox11(cXY, lane, hXY);
#pragma unroll
    for (int j = 0; j < 8; ++j) {
      const float mu_x = hX[j] * WSCALE;
      const float mu_y = hY[j] * WSCALE;
      const float ex2  = hXX[j] * WSCALE;
      const float ey2  = hYY[j] * WSCALE;
      const float exy  = hXY[j] * WSCALE;
      const float mxx = mu_x * mu_x;
      const float myy = mu_y * mu_y;
      const float mxy = mu_x * mu_y;
      const float num = fmaf(2.f, mxy, C1F) * fmaf(2.f, exy - mxy, C2F);
      const float den = (mxx + myy + C1F) * ((ex2 - mxx) + (ey2 - myy) + C2F);
      acc += num * __builtin_amdgcn_rcpf(den);
    }
  };

  // spin-up: accumulate rows r0 .. r0+9 (out-of-range rows contribute zero)
  for (int i = 0; i < 10; ++i) add_row(r0 + i);

  // first output row: window rows r0..r0+10 -> output O0
  add_row(r0 + 10);
  emit_row();

  // steady state: outputs O0+1 .. O0+BAND-1
  for (int i = 11; i < 10 + BAND; ++i) {
    add_row(r0 + i);
    sub_row(r0 + i - 11);
    emit_row();
  }

  // per-wave reduction, one partial per wave (no cross-wave sync needed)
#pragma unroll
  for (int off = 32; off > 0; off >>= 1) acc += __shfl_down(acc, off, 64);
  if (lane == 0) {
    if (ATOMIC) {
      atomicAdd(out_ws, acc);
    } else {
      out_ws[(size_t)z * BANDS + band] = acc;
    }
  }
}

__global__ void ssim_finalize(const float* __restrict__ partials, int n,
                              float* __restrict__ out) {
  __shared__ float wsum[4];
  float acc = 0.f;
  for (int i = threadIdx.x; i < n; i += 256) acc += partials[i];
#pragma unroll
  for (int off = 32; off > 0; off >>= 1) acc += __shfl_down(acc, off, 64);
  if ((threadIdx.x & 63) == 0) wsum[threadIdx.x >> 6] = acc;
  __syncthreads();
  if (threadIdx.x == 0) {
    const float t = wsum[0] + wsum[1] + wsum[2] + wsum[3];
    out[0] = 1.0f - t * (1.0f / (64.0f * 512.0f * 512.0f));
  }
}

__global__ void ssim_zero(float* p) {
  if (threadIdx.x == 0) p[0] = 0.f;
}

__global__ void ssim_finalize_atomic(const float* __restrict__ accp,
                                     float* __restrict__ out) {
  if (threadIdx.x == 0)
    out[0] = 1.0f - accp[0] * (1.0f / (64.0f * 512.0f * 512.0f));
}

extern "C" void kernel_launch(void* const* d_in, const int* in_sizes, int n_in,
                              void* d_out, int out_size, void* d_ws, size_t ws_size,
                              hipStream_t stream) {
  const float* x = (const float*)d_in[0];
  const float* y = (const float*)d_in[1];
  // d_in[2]: uniform 1/121 window, folded into WSCALE.
  float* out = (float*)d_out;

  dim3 grid(BX, 64);      // 32 x 64 = 2048 blocks, 8192 independent waves
  dim3 block(256);
  const int npart = BANDS * 64;   // one partial per wave = 8192

  if (ws_size >= (size_t)npart * sizeof(float)) {
    float* partials = (float*)d_ws;
    ssim_main<false><<<grid, block, 0, stream>>>(x, y, partials);
    ssim_finalize<<<1, 256, 0, stream>>>(partials, npart, out);
  } else {
    float* accp = (float*)d_ws;
    ssim_zero<<<1, 64, 0, stream>>>(accp);
    ssim_main<true><<<grid, block, 0, stream>>>(x, y, accp);
    ssim_finalize_atomic<<<1, 64, 0, stream>>>(accp, out);
  }
}

// Round 6
// 200.584 us; speedup vs baseline: 2.0425x; 2.0425x over previous
//
#include <hip/hip_runtime.h>

// SSIM, 64 slices of 512x512, 11x11 uniform window (separable box), zero pad.
// R6: BAND=4 (8192 waves, 8 blocks/CU) but WITHOUT the R5 register squeeze.
// R5 post-mortem: __launch_bounds__(256,8) forced VGPR 52->32, spilling the
// accumulator arrays to scratch (WRITE_SIZE 34KB -> 568MB, VALUBusy 0.8%).
// Natural VGPR (~52) already permits 8 waves/SIMD (floor(512/52)=9, cap 8),
// so declare only a floor of 4 waves/EU and let the allocator breathe.
//  - each wave owns a 4-output-row band x full 512 cols (8 cols/lane).
//  - vertical running box sums in registers; "subtract row r-11" re-loaded
//    from global (L2/L3-hot).
//  - horizontal 11-box via 10 lane shuffles per quantity (conflict-free).

constexpr int IMG    = 512;
constexpr int BAND   = 4;                       // output rows per wave
constexpr int BANDS  = IMG / BAND;              // 128
constexpr int WPB    = 4;                       // waves per block
constexpr int BX     = BANDS / WPB;             // 32 blocks in x
constexpr float WSCALE = 1.0f / 121.0f;
constexpr float C1F = 1e-4f;                    // 0.01^2
constexpr float C2F = 9e-4f;                    // 0.03^2

__device__ __forceinline__ float shl1(float v, int lane) {  // lane g-1's v, 0 at g==0
  const float t = __shfl_up(v, 1, 64);
  return lane == 0 ? 0.f : t;
}
__device__ __forceinline__ float shr1(float v, int lane) {  // lane g+1's v, 0 at g==63
  const float t = __shfl_down(v, 1, 64);
  return lane == 63 ? 0.f : t;
}

// horizontal 11-wide box sum of per-column sums c[0..7] (cols 8g..8g+7),
// zero padding outside [0,512). h[j] = sum cols (8g+j-5 .. 8g+j+5).
__device__ __forceinline__ void hbox11(const float c[8], int lane, float h[8]) {
  float w[18];
  w[0] = shl1(c[3], lane);
  w[1] = shl1(c[4], lane);
  w[2] = shl1(c[5], lane);
  w[3] = shl1(c[6], lane);
  w[4] = shl1(c[7], lane);
#pragma unroll
  for (int k = 0; k < 8; ++k) w[5 + k] = c[k];
  w[13] = shr1(c[0], lane);
  w[14] = shr1(c[1], lane);
  w[15] = shr1(c[2], lane);
  w[16] = shr1(c[3], lane);
  w[17] = shr1(c[4], lane);
  float s = w[0];
#pragma unroll
  for (int k = 1; k <= 10; ++k) s += w[k];
  h[0] = s;
#pragma unroll
  for (int j = 1; j < 8; ++j) { s += w[j + 10] - w[j - 1]; h[j] = s; }
}

template <bool ATOMIC>
__global__ __launch_bounds__(256, 4) void ssim_main(const float* __restrict__ x,
                                                    const float* __restrict__ y,
                                                    float* __restrict__ out_ws) {
  const int tid  = threadIdx.x;
  const int lane = tid & 63;
  const int wv   = tid >> 6;
  const int band = blockIdx.x * WPB + wv;   // 0..127
  const int z    = blockIdx.y;              // 0..63
  const int O0   = band * BAND;             // first output row
  const int r0   = O0 - 5;                  // first streamed input row
  const float* xs = x + (size_t)z * IMG * IMG;
  const float* ys = y + (size_t)z * IMG * IMG;
  const int c0   = lane * 8;

  float cX[8]  = {0.f,0.f,0.f,0.f,0.f,0.f,0.f,0.f};
  float cY[8]  = {0.f,0.f,0.f,0.f,0.f,0.f,0.f,0.f};
  float cXX[8] = {0.f,0.f,0.f,0.f,0.f,0.f,0.f,0.f};
  float cYY[8] = {0.f,0.f,0.f,0.f,0.f,0.f,0.f,0.f};
  float cXY[8] = {0.f,0.f,0.f,0.f,0.f,0.f,0.f,0.f};
  float acc = 0.f;

  auto add_row = [&](int gr) {
    if ((unsigned)gr < (unsigned)IMG) {       // wave-uniform branch
      const float4 a0 = *(const float4*)(xs + (size_t)gr * IMG + c0);
      const float4 a1 = *(const float4*)(xs + (size_t)gr * IMG + c0 + 4);
      const float4 b0 = *(const float4*)(ys + (size_t)gr * IMG + c0);
      const float4 b1 = *(const float4*)(ys + (size_t)gr * IMG + c0 + 4);
      float vx[8] = {a0.x, a0.y, a0.z, a0.w, a1.x, a1.y, a1.z, a1.w};
      float vy[8] = {b0.x, b0.y, b0.z, b0.w, b1.x, b1.y, b1.z, b1.w};
#pragma unroll
      for (int k = 0; k < 8; ++k) {
        cX[k] += vx[k];
        cY[k] += vy[k];
        cXX[k] = fmaf(vx[k], vx[k], cXX[k]);
        cYY[k] = fmaf(vy[k], vy[k], cYY[k]);
        cXY[k] = fmaf(vx[k], vy[k], cXY[k]);
      }
    }
  };
  auto sub_row = [&](int gr) {
    if (gr >= r0 && (unsigned)gr < (unsigned)IMG) {   // never-added rows skipped
      const float4 a0 = *(const float4*)(xs + (size_t)gr * IMG + c0);
      const float4 a1 = *(const float4*)(xs + (size_t)gr * IMG + c0 + 4);
      const float4 b0 = *(const float4*)(ys + (size_t)gr * IMG + c0);
      const float4 b1 = *(const float4*)(ys + (size_t)gr * IMG + c0 + 4);
      float vx[8] = {a0.x, a0.y, a0.z, a0.w, a1.x, a1.y, a1.z, a1.w};
      float vy[8] = {b0.x, b0.y, b0.z, b0.w, b1.x, b1.y, b1.z, b1.w};
#pragma unroll
      for (int k = 0; k < 8; ++k) {
        cX[k] -= vx[k];
        cY[k] -= vy[k];
        cXX[k] = fmaf(-vx[k], vx[k], cXX[k]);
        cYY[k] = fmaf(-vy[k], vy[k], cYY[k]);
        cXY[k] = fmaf(-vx[k], vy[k], cXY[k]);
      }
    }
  };
  auto emit_row = [&]() {
    float hX[8], hY[8], hXX[8], hYY[8], hXY[8];
    hbox11(cX,  lane, hX);
    hbox11(cY,  lane, hY);
    hbox11(cXX, lane, hXX);
    hbox11(cYY, lane, hYY);
    hbox11(cXY, lane, hXY);
#pragma unroll
    for (int j = 0; j < 8; ++j) {
      const float mu_x = hX[j] * WSCALE;
      const float mu_y = hY[j] * WSCALE;
      const float ex2  = hXX[j] * WSCALE;
      const float ey2  = hYY[j] * WSCALE;
      const float exy  = hXY[j] * WSCALE;
      const float mxx = mu_x * mu_x;
      const float myy = mu_y * mu_y;
      const float mxy = mu_x * mu_y;
      const float num = fmaf(2.f, mxy, C1F) * fmaf(2.f, exy - mxy, C2F);
      const float den = (mxx + myy + C1F) * ((ex2 - mxx) + (ey2 - myy) + C2F);
      acc += num * __builtin_amdgcn_rcpf(den);
    }
  };

  // spin-up: accumulate rows r0 .. r0+9 (out-of-range rows contribute zero)
  for (int i = 0; i < 10; ++i) add_row(r0 + i);

  // first output row: window rows r0..r0+10 -> output O0
  add_row(r0 + 10);
  emit_row();

  // steady state: outputs O0+1 .. O0+BAND-1
  for (int i = 11; i < 10 + BAND; ++i) {
    add_row(r0 + i);
    sub_row(r0 + i - 11);
    emit_row();
  }

  // per-wave reduction, one partial per wave (no cross-wave sync needed)
#pragma unroll
  for (int off = 32; off > 0; off >>= 1) acc += __shfl_down(acc, off, 64);
  if (lane == 0) {
    if (ATOMIC) {
      atomicAdd(out_ws, acc);
    } else {
      out_ws[(size_t)z * BANDS + band] = acc;
    }
  }
}

__global__ void ssim_finalize(const float* __restrict__ partials, int n,
                              float* __restrict__ out) {
  __shared__ float wsum[4];
  float acc = 0.f;
  for (int i = threadIdx.x; i < n; i += 256) acc += partials[i];
#pragma unroll
  for (int off = 32; off > 0; off >>= 1) acc += __shfl_down(acc, off, 64);
  if ((threadIdx.x & 63) == 0) wsum[threadIdx.x >> 6] = acc;
  __syncthreads();
  if (threadIdx.x == 0) {
    const float t = wsum[0] + wsum[1] + wsum[2] + wsum[3];
    out[0] = 1.0f - t * (1.0f / (64.0f * 512.0f * 512.0f));
  }
}

__global__ void ssim_zero(float* p) {
  if (threadIdx.x == 0) p[0] = 0.f;
}

__global__ void ssim_finalize_atomic(const float* __restrict__ accp,
                                     float* __restrict__ out) {
  if (threadIdx.x == 0)
    out[0] = 1.0f - accp[0] * (1.0f / (64.0f * 512.0f * 512.0f));
}

extern "C" void kernel_launch(void* const* d_in, const int* in_sizes, int n_in,
                              void* d_out, int out_size, void* d_ws, size_t ws_size,
                              hipStream_t stream) {
  const float* x = (const float*)d_in[0];
  const float* y = (const float*)d_in[1];
  // d_in[2]: uniform 1/121 window, folded into WSCALE.
  float* out = (float*)d_out;

  dim3 grid(BX, 64);      // 32 x 64 = 2048 blocks, 8192 independent waves
  dim3 block(256);
  const int npart = BANDS * 64;   // one partial per wave = 8192

  if (ws_size >= (size_t)npart * sizeof(float)) {
    float* partials = (float*)d_ws;
    ssim_main<false><<<grid, block, 0, stream>>>(x, y, partials);
    ssim_finalize<<<1, 256, 0, stream>>>(partials, npart, out);
  } else {
    float* accp = (float*)d_ws;
    ssim_zero<<<1, 64, 0, stream>>>(accp);
    ssim_main<true><<<grid, block, 0, stream>>>(x, y, accp);
    ssim_finalize_atomic<<<1, 64, 0, stream>>>(accp, out);
  }
}

// Round 9
// 190.241 us; speedup vs baseline: 2.1535x; 1.0544x over previous
//
#include <hip/hip_runtime.h>

// SSIM, 64 slices of 512x512, 11x11 uniform window (separable box), zero pad.
// R9 = R7/R8 resubmitted (both failed with "MI355X container failed twice"
// before running anything — no compile error, no absmax; diff vs known-good
// R6 is only scalar index math, so infra flake is the prior). Hedge: grid
// expressed as 2-D (16,64) like R6, linear id reconstructed for the swizzle
// (identical dispatch linearization).
// Design: R4 (BAND=8 wave-autonomous, VGPR 52, no launch-bounds squeeze)
// + XCD locality swizzle. Latency-bound per R6 counters (VALU 28%, HBM 38%,
// occ 39%): all 16 blocks of a slice land on one XCD (lin%8), vertically-
// adjacent band-blocks consecutive -> halo + subtract re-reads served by the
// local 4MB L2 (~200cy) instead of L3/HBM (~600-900cy).
//  - each wave owns an 8-output-row band x full 512 cols (8 cols/lane).
//  - vertical running box sums in registers; "subtract row r-11" re-loaded
//    from global (now L2-local).
//  - horizontal 11-box via 10 lane shuffles per quantity (conflict-free).

constexpr int IMG    = 512;
constexpr int BAND   = 8;                       // output rows per wave
constexpr int BANDS  = IMG / BAND;              // 64
constexpr int WPB    = 4;                       // waves per block
constexpr int BX     = BANDS / WPB;             // 16 blocks per slice
constexpr float WSCALE = 1.0f / 121.0f;
constexpr float C1F = 1e-4f;                    // 0.01^2
constexpr float C2F = 9e-4f;                    // 0.03^2

__device__ __forceinline__ float shl1(float v, int lane) {  // lane g-1's v, 0 at g==0
  const float t = __shfl_up(v, 1, 64);
  return lane == 0 ? 0.f : t;
}
__device__ __forceinline__ float shr1(float v, int lane) {  // lane g+1's v, 0 at g==63
  const float t = __shfl_down(v, 1, 64);
  return lane == 63 ? 0.f : t;
}

// horizontal 11-wide box sum of per-column sums c[0..7] (cols 8g..8g+7),
// zero padding outside [0,512). h[j] = sum cols (8g+j-5 .. 8g+j+5).
__device__ __forceinline__ void hbox11(const float c[8], int lane, float h[8]) {
  float w[18];
  w[0] = shl1(c[3], lane);
  w[1] = shl1(c[4], lane);
  w[2] = shl1(c[5], lane);
  w[3] = shl1(c[6], lane);
  w[4] = shl1(c[7], lane);
#pragma unroll
  for (int k = 0; k < 8; ++k) w[5 + k] = c[k];
  w[13] = shr1(c[0], lane);
  w[14] = shr1(c[1], lane);
  w[15] = shr1(c[2], lane);
  w[16] = shr1(c[3], lane);
  w[17] = shr1(c[4], lane);
  float s = w[0];
#pragma unroll
  for (int k = 1; k <= 10; ++k) s += w[k];
  h[0] = s;
#pragma unroll
  for (int j = 1; j < 8; ++j) { s += w[j + 10] - w[j - 1]; h[j] = s; }
}

template <bool ATOMIC>
__global__ __launch_bounds__(256) void ssim_main(const float* __restrict__ x,
                                                 const float* __restrict__ y,
                                                 float* __restrict__ out_ws) {
  const int tid  = threadIdx.x;
  const int lane = tid & 63;
  const int wv   = tid >> 6;

  // XCD-clustering swizzle on the linearized dispatch id (x-major):
  // XCD = lin % 8 (dispatch heuristic). All 16 blocks of slice z land on
  // one XCD; band-blocks consecutive in k_ so vertically-adjacent blocks
  // are co-resident on that XCD.
  const int lin  = blockIdx.x + BX * blockIdx.y;  // 0..1023
  const int c_   = lin & 7;              // XCD id
  const int k_   = lin >> 3;             // 0..127
  const int z    = c_ + 8 * (k_ >> 4);   // 8 slices per XCD
  const int bblk = k_ & 15;              // band-block within slice
  const int band = bblk * WPB + wv;      // 0..63
  const int O0   = band * BAND;          // first output row
  const int r0   = O0 - 5;               // first streamed input row
  const float* xs = x + (size_t)z * IMG * IMG;
  const float* ys = y + (size_t)z * IMG * IMG;
  const int c0   = lane * 8;

  float cX[8]  = {0.f,0.f,0.f,0.f,0.f,0.f,0.f,0.f};
  float cY[8]  = {0.f,0.f,0.f,0.f,0.f,0.f,0.f,0.f};
  float cXX[8] = {0.f,0.f,0.f,0.f,0.f,0.f,0.f,0.f};
  float cYY[8] = {0.f,0.f,0.f,0.f,0.f,0.f,0.f,0.f};
  float cXY[8] = {0.f,0.f,0.f,0.f,0.f,0.f,0.f,0.f};
  float acc = 0.f;

  auto add_row = [&](int gr) {
    if ((unsigned)gr < (unsigned)IMG) {       // wave-uniform branch
      const float4 a0 = *(const float4*)(xs + (size_t)gr * IMG + c0);
      const float4 a1 = *(const float4*)(xs + (size_t)gr * IMG + c0 + 4);
      const float4 b0 = *(const float4*)(ys + (size_t)gr * IMG + c0);
      const float4 b1 = *(const float4*)(ys + (size_t)gr * IMG + c0 + 4);
      float vx[8] = {a0.x, a0.y, a0.z, a0.w, a1.x, a1.y, a1.z, a1.w};
      float vy[8] = {b0.x, b0.y, b0.z, b0.w, b1.x, b1.y, b1.z, b1.w};
#pragma unroll
      for (int k = 0; k < 8; ++k) {
        cX[k] += vx[k];
        cY[k] += vy[k];
        cXX[k] = fmaf(vx[k], vx[k], cXX[k]);
        cYY[k] = fmaf(vy[k], vy[k], cYY[k]);
        cXY[k] = fmaf(vx[k], vy[k], cXY[k]);
      }
    }
  };
  auto sub_row = [&](int gr) {
    if (gr >= r0 && (unsigned)gr < (unsigned)IMG) {   // never-added rows skipped
      const float4 a0 = *(const float4*)(xs + (size_t)gr * IMG + c0);
      const float4 a1 = *(const float4*)(xs + (size_t)gr * IMG + c0 + 4);
      const float4 b0 = *(const float4*)(ys + (size_t)gr * IMG + c0);
      const float4 b1 = *(const float4*)(ys + (size_t)gr * IMG + c0 + 4);
      float vx[8] = {a0.x, a0.y, a0.z, a0.w, a1.x, a1.y, a1.z, a1.w};
      float vy[8] = {b0.x, b0.y, b0.z, b0.w, b1.x, b1.y, b1.z, b1.w};
#pragma unroll
      for (int k = 0; k < 8; ++k) {
        cX[k] -= vx[k];
        cY[k] -= vy[k];
        cXX[k] = fmaf(-vx[k], vx[k], cXX[k]);
        cYY[k] = fmaf(-vy[k], vy[k], cYY[k]);
        cXY[k] = fmaf(-vx[k], vy[k], cXY[k]);
      }
    }
  };
  auto emit_row = [&]() {
    float hX[8], hY[8], hXX[8], hYY[8], hXY[8];
    hbox11(cX,  lane, hX);
    hbox11(cY,  lane, hY);
    hbox11(cXX, lane, hXX);
    hbox11(cYY, lane, hYY);
    hbox11(cXY, lane, hXY);
#pragma unroll
    for (int j = 0; j < 8; ++j) {
      const float mu_x = hX[j] * WSCALE;
      const float mu_y = hY[j] * WSCALE;
      const float ex2  = hXX[j] * WSCALE;
      const float ey2  = hYY[j] * WSCALE;
      const float exy  = hXY[j] * WSCALE;
      const float mxx = mu_x * mu_x;
      const float myy = mu_y * mu_y;
      const float mxy = mu_x * mu_y;
      const float num = fmaf(2.f, mxy, C1F) * fmaf(2.f, exy - mxy, C2F);
      const float den = (mxx + myy + C1F) * ((ex2 - mxx) + (ey2 - myy) + C2F);
      acc += num * __builtin_amdgcn_rcpf(den);
    }
  };

  // spin-up: accumulate rows r0 .. r0+9 (out-of-range rows contribute zero)
  for (int i = 0; i < 10; ++i) add_row(r0 + i);

  // first output row: window rows r0..r0+10 -> output O0
  add_row(r0 + 10);
  emit_row();

  // steady state: outputs O0+1 .. O0+BAND-1
  for (int i = 11; i < 10 + BAND; ++i) {
    add_row(r0 + i);
    sub_row(r0 + i - 11);
    emit_row();
  }

  // per-wave reduction, one partial per wave (no cross-wave sync needed)
#pragma unroll
  for (int off = 32; off > 0; off >>= 1) acc += __shfl_down(acc, off, 64);
  if (lane == 0) {
    if (ATOMIC) {
      atomicAdd(out_ws, acc);
    } else {
      out_ws[(size_t)z * BANDS + band] = acc;
    }
  }
}

__global__ void ssim_finalize(const float* __restrict__ partials, int n,
                              float* __restrict__ out) {
  __shared__ float wsum[4];
  float acc = 0.f;
  for (int i = threadIdx.x; i < n; i += 256) acc += partials[i];
#pragma unroll
  for (int off = 32; off > 0; off >>= 1) acc += __shfl_down(acc, off, 64);
  if ((threadIdx.x & 63) == 0) wsum[threadIdx.x >> 6] = acc;
  __syncthreads();
  if (threadIdx.x == 0) {
    const float t = wsum[0] + wsum[1] + wsum[2] + wsum[3];
    out[0] = 1.0f - t * (1.0f / (64.0f * 512.0f * 512.0f));
  }
}

__global__ void ssim_zero(float* p) {
  if (threadIdx.x == 0) p[0] = 0.f;
}

__global__ void ssim_finalize_atomic(const float* __restrict__ accp,
                                     float* __restrict__ out) {
  if (threadIdx.x == 0)
    out[0] = 1.0f - accp[0] * (1.0f / (64.0f * 512.0f * 512.0f));
}

extern "C" void kernel_launch(void* const* d_in, const int* in_sizes, int n_in,
                              void* d_out, int out_size, void* d_ws, size_t ws_size,
                              hipStream_t stream) {
  const float* x = (const float*)d_in[0];
  const float* y = (const float*)d_in[1];
  // d_in[2]: uniform 1/121 window, folded into WSCALE.
  float* out = (float*)d_out;

  dim3 grid(BX, 64);      // 16 x 64 = 1024 blocks (same shape as R6), 4096 waves
  dim3 block(256);
  const int npart = BANDS * 64;   // one partial per wave = 4096

  if (ws_size >= (size_t)npart * sizeof(float)) {
    float* partials = (float*)d_ws;
    ssim_main<false><<<grid, block, 0, stream>>>(x, y, partials);
    ssim_finalize<<<1, 256, 0, stream>>>(partials, npart, out);
  } else {
    float* accp = (float*)d_ws;
    ssim_zero<<<1, 64, 0, stream>>>(accp);
    ssim_main<true><<<grid, block, 0, stream>>>(x, y, accp);
    ssim_finalize_atomic<<<1, 64, 0, stream>>>(accp, out);
  }
}